// Round 2
// baseline (2564.505 us; speedup 1.0000x reference)
//
#include <hip/hip_runtime.h>
#include <math.h>

// Problem constants (from reference setup_inputs)
#define N_    32
#define C_    512
#define T_    2048
#define G_    4
#define K_    1024
#define DG    128
#define NTOK  (N_ * T_)          // 65536 tokens
#define NCT   ((size_t)N_ * C_ * T_)

// ---------------------------------------------------------------------------
// K0: per-code squared norms  cnorm[g*K + k] = sum_d cb[g,k,d]^2
// ---------------------------------------------------------------------------
__global__ void k_cnorm(const float* __restrict__ cb, float* __restrict__ cnorm) {
    int i = blockIdx.x * 256 + threadIdx.x;          // 0 .. G*K-1
    const float4* row = (const float4*)(cb + (size_t)i * DG);
    float s0 = 0.f, s1 = 0.f, s2 = 0.f, s3 = 0.f;
#pragma unroll
    for (int d = 0; d < DG / 4; ++d) {
        float4 v = row[d];
        s0 = fmaf(v.x, v.x, s0);
        s1 = fmaf(v.y, v.y, s1);
        s2 = fmaf(v.z, v.z, s2);
        s3 = fmaf(v.w, v.w, s3);
    }
    cnorm[i] = (s0 + s1) + (s2 + s3);
}

// ---------------------------------------------------------------------------
// K1: argmin over codes.  One thread = one (token, group).
//     Code rows are WAVE-UNIFORM -> stream them through the scalar pipe
//     (s_load_dwordx16) and feed v_fmac_f32 with an SGPR operand. No LDS.
//     x stays resident in 128 VGPRs per thread.
// ---------------------------------------------------------------------------
__global__ void __launch_bounds__(256) k_argmin(const float* __restrict__ x,
                                                const float* __restrict__ cb,
                                                const float* __restrict__ cnorm,
                                                int* __restrict__ code_idx,
                                                float* __restrict__ counts) {
    const int g     = blockIdx.y;
    const int token = blockIdx.x * 256 + threadIdx.x;
    const int b     = token >> 11;                   // T = 2048
    const int t     = token & (T_ - 1);

    // x layout (N, C, T): element (b, g*128+d, t). Lane -> t : coalesced.
    const float* xp = x + ((size_t)b * C_ + g * DG) * T_ + t;
    float xr[DG];
#pragma unroll
    for (int d = 0; d < DG; ++d) xr[d] = xp[(size_t)d * T_];

    float best  = 3.4e38f;
    int   bestk = 0;
    const float* __restrict__ cng = cnorm + g * K_;
    const float* __restrict__ cbg = cb + (size_t)g * K_ * DG;

#pragma unroll 2
    for (int k = 0; k < K_; ++k) {
        const float* crow = cbg + (size_t)k * DG;    // wave-uniform -> s_load
        float a0 = 0.f, a1 = 0.f, a2 = 0.f, a3 = 0.f;
#pragma unroll
        for (int d = 0; d < DG; d += 4) {
            a0 = fmaf(xr[d + 0], crow[d + 0], a0);   // v_fmac v, s, v
            a1 = fmaf(xr[d + 1], crow[d + 1], a1);
            a2 = fmaf(xr[d + 2], crow[d + 2], a2);
            a3 = fmaf(xr[d + 3], crow[d + 3], a3);
        }
        float dot  = (a0 + a1) + (a2 + a3);
        float dist = fmaf(-2.f, dot, cng[k]);
        if (dist < best) { best = dist; bestk = k; } // first-min tie semantics
    }

    code_idx[(size_t)g * NTOK + token] = bestk;
    atomicAdd(&counts[g * K_ + bestk], 1.0f);
}

// ---------------------------------------------------------------------------
// K2: dequantize + write out (N,C,T) + loss partial sums.
//     One thread = one token; gathers code rows as float4 (L2-resident).
// ---------------------------------------------------------------------------
__global__ void __launch_bounds__(256) k_dequant(const float* __restrict__ x,
                                                 const float* __restrict__ cb,
                                                 const int* __restrict__ code_idx,
                                                 float* __restrict__ out,
                                                 float* __restrict__ loss_acc) {
    const int token = blockIdx.x * 256 + threadIdx.x;
    const int b     = token >> 11;
    const int t     = token & (T_ - 1);
    const size_t base = (size_t)b * C_ * T_ + t;

    float lsum = 0.f;
#pragma unroll
    for (int g = 0; g < G_; ++g) {
        const int idx = code_idx[(size_t)g * NTOK + token];
        const float4* row = (const float4*)(cb + ((size_t)g * K_ + idx) * DG);
        for (int d4 = 0; d4 < DG / 4; ++d4) {
            float4 v = row[d4];                      // 16B gather, L2-resident
            const int c = g * DG + d4 * 4;
            float x0 = x[base + (size_t)(c + 0) * T_];
            float x1 = x[base + (size_t)(c + 1) * T_];
            float x2 = x[base + (size_t)(c + 2) * T_];
            float x3 = x[base + (size_t)(c + 3) * T_];
            out[base + (size_t)(c + 0) * T_] = v.x;
            out[base + (size_t)(c + 1) * T_] = v.y;
            out[base + (size_t)(c + 2) * T_] = v.z;
            out[base + (size_t)(c + 3) * T_] = v.w;
            float d0 = v.x - x0, d1 = v.y - x1, d2 = v.z - x2, d3 = v.w - x3;
            lsum += d0 * d0 + d1 * d1 + d2 * d2 + d3 * d3;
        }
    }
    // wave(64)-level reduction, one atomic per wave
#pragma unroll
    for (int off = 32; off >= 1; off >>= 1)
        lsum += __shfl_down(lsum, off, 64);
    if ((threadIdx.x & 63) == 0) atomicAdd(loss_acc, lsum);
}

// ---------------------------------------------------------------------------
// K3: finalize loss & perplexity scalars.
// ---------------------------------------------------------------------------
__global__ void k_final(const float* __restrict__ counts,
                        const float* __restrict__ loss_acc,
                        float* __restrict__ out_scalars) {
    const int w    = threadIdx.x >> 6;               // wave = group
    const int lane = threadIdx.x & 63;
    float s = 0.f;
    for (int j = lane; j < K_; j += 64) {
        float p = counts[w * K_ + j] * (1.0f / NTOK);
        s += p * logf(p + 1e-10f);
    }
#pragma unroll
    for (int off = 32; off >= 1; off >>= 1)
        s += __shfl_down(s, off, 64);
    __shared__ float sg[4];
    if (lane == 0) sg[w] = s;
    __syncthreads();
    if (threadIdx.x == 0) {
        float perp = 0.f;
#pragma unroll
        for (int g = 0; g < G_; ++g) perp += expf(-sg[g]);
        perp *= 0.25f;
        float loss = 1.25f * loss_acc[0] / (float)((size_t)NTOK * C_);
        out_scalars[0] = loss;
        out_scalars[1] = perp;
    }
}

// ---------------------------------------------------------------------------
extern "C" void kernel_launch(void* const* d_in, const int* in_sizes, int n_in,
                              void* d_out, int out_size, void* d_ws, size_t ws_size,
                              hipStream_t stream) {
    const float* x  = (const float*)d_in[0];
    const float* cb = (const float*)d_in[1];
    float* out = (float*)d_out;

    char*  ws       = (char*)d_ws;
    int*   code_idx = (int*)ws;                              // NTOK*G ints (1 MiB)
    float* cnorm    = (float*)(ws + (size_t)NTOK * G_ * 4);  // G*K floats
    float* counts   = cnorm + G_ * K_;                       // G*K floats
    float* loss_acc = counts + G_ * K_;                      // 1 float

    // ws is poisoned before every launch: zero the accumulators.
    hipMemsetAsync(counts, 0, (G_ * K_ + 1) * sizeof(float), stream);

    k_cnorm<<<G_ * K_ / 256, 256, 0, stream>>>(cb, cnorm);

    dim3 ga(NTOK / 256, G_);
    k_argmin<<<ga, 256, 0, stream>>>(x, cb, cnorm, code_idx, counts);

    k_dequant<<<NTOK / 256, 256, 0, stream>>>(x, cb, code_idx, out, loss_acc);

    k_final<<<1, 256, 0, stream>>>(counts, loss_acc, out + NCT);
}

// Round 4
// 782.478 us; speedup vs baseline: 3.2774x; 3.2774x over previous
//
#include <hip/hip_runtime.h>
#include <math.h>

// Problem constants (from reference setup_inputs)
#define N_    32
#define C_    512
#define T_    2048
#define G_    4
#define K_    1024
#define DG    128
#define NTOK  (N_ * T_)          // 65536 tokens
#define NCT   ((size_t)N_ * C_ * T_)

#define DELTA 2e-3f              // top-2 gap below which we rescore in exact fp32

typedef _Float16 f16x8 __attribute__((ext_vector_type(8)));
typedef float    f32x4 __attribute__((ext_vector_type(4)));

// ws layout (bytes) — total footprint 0x410000 (~4.06 MiB)
#define OFF_CODEIDX 0x000000     // NTOK*G int            (1 MiB)
#define OFF_CNORM   0x100000     // G*K float             (16 KiB)
#define OFF_COUNTS  0x104000     // G*K float             (16 KiB)
#define OFF_LOSS    0x108000     // 1 float
#define OFF_FLAGCNT 0x108004     // 1 uint
#define OFF_FLAGS   0x108010     // up to NTOK*G uint     (1 MiB)
#define OFF_CBH     0x210000     // G*2*8*128*64 fp16     (1 MiB)
#define OFF_CBL     0x310000     // same                  (1 MiB)

__device__ inline unsigned int pack2h(float a, float b) {
    _Float16 ha = (_Float16)a, hb = (_Float16)b;
    unsigned short ba, bb;
    __builtin_memcpy(&ba, &ha, 2);
    __builtin_memcpy(&bb, &hb, 2);
    return (unsigned int)ba | ((unsigned int)bb << 16);
}

// ---------------------------------------------------------------------------
// K0a: per-code squared norms (fp32)
// ---------------------------------------------------------------------------
__global__ void k_cnorm(const float* __restrict__ cb, float* __restrict__ cnorm) {
    int i = blockIdx.x * 256 + threadIdx.x;          // 0 .. G*K-1
    const float4* row = (const float4*)(cb + (size_t)i * DG);
    float s0 = 0.f, s1 = 0.f, s2 = 0.f, s3 = 0.f;
#pragma unroll
    for (int d = 0; d < DG / 4; ++d) {
        float4 v = row[d];
        s0 = fmaf(v.x, v.x, s0);
        s1 = fmaf(v.y, v.y, s1);
        s2 = fmaf(v.z, v.z, s2);
        s3 = fmaf(v.w, v.w, s3);
    }
    cnorm[i] = (s0 + s1) + (s2 + s3);
}

// ---------------------------------------------------------------------------
// K0b: codebook fp32 -> fp16 hi/lo slabs.
// Slab id = (g*2 + ks)*8 + ct (ks = 64-dim half, ct = 128-code tile);
// within slab: [code_local 0..127][kk 0..63] fp16 (128 B per code row).
// ---------------------------------------------------------------------------
__global__ void k_prep_cb(const float* __restrict__ cb,
                          unsigned short* __restrict__ cbh,
                          unsigned short* __restrict__ cbl) {
    const int ct = blockIdx.x, g = blockIdx.y;
    const int code = threadIdx.x & 127, ks = threadIdx.x >> 7;
    const float4* src = (const float4*)(cb + ((size_t)(g * K_ + ct * 128 + code)) * DG + ks * 64);
    unsigned int* dh = (unsigned int*)cbh + ((size_t)((g * 2 + ks) * 8 + ct)) * 4096 + code * 32;
    unsigned int* dl = (unsigned int*)cbl + ((size_t)((g * 2 + ks) * 8 + ct)) * 4096 + code * 32;
#pragma unroll
    for (int j = 0; j < 16; ++j) {
        float4 v = src[j];
        dh[2 * j]     = pack2h(v.x, v.y);
        dh[2 * j + 1] = pack2h(v.z, v.w);
        float lx = v.x - (float)(_Float16)v.x;
        float ly = v.y - (float)(_Float16)v.y;
        float lz = v.z - (float)(_Float16)v.z;
        float lw = v.w - (float)(_Float16)v.w;
        dl[2 * j]     = pack2h(lx, ly);
        dl[2 * j + 1] = pack2h(lz, lw);
    }
}

// ---------------------------------------------------------------------------
// K1: MFMA screen. Block = 64 tokens x all 1024 codes of one group.
//   A (x) hi/lo staged once into 4 swizzled LDS slabs (32 KiB).
//   B (codes) double-buffered 16 KiB slabs (128 codes x 64 k), reg-staged.
//   Virtual K = 384: xh*ch + xh*cl + xl*ch. Top-2 tracked per token;
//   gap <= DELTA -> flagged for exact fp32 fallback.
// ---------------------------------------------------------------------------
__global__ void __launch_bounds__(256) k_screen(
        const float* __restrict__ x,
        const unsigned short* __restrict__ cbh,
        const unsigned short* __restrict__ cbl,
        const float* __restrict__ cnorm,
        int* __restrict__ code_idx, float* __restrict__ counts,
        unsigned int* __restrict__ flag_count, unsigned int* __restrict__ flag_list) {
    __shared__ __align__(16) char smem[65536];   // [0,32K): A slabs; [32K,64K): B dbuf

    const int tt = blockIdx.x, g = blockIdx.y;
    const int tid = threadIdx.x;
    const int wn = tid >> 6, lane = tid & 63, q = lane >> 4, r15 = lane & 15;

    // ---- stage A: 64 tokens x 128 dims -> 4 slabs (hi/lo x ks), swizzled
    {
        const int tok = lane;
        const int token = tt * 64 + tok;
        const int b = token >> 11, t = token & (T_ - 1);
        const float* xb = x + ((size_t)b * C_ + g * DG) * T_ + t;
        const int swz_w = (tok & 7) << 4;
#pragma unroll
        for (int i = 0; i < 16; ++i) {
            int j = wn + 4 * i;              // pair j covers c = 2j, 2j+1
            int c0 = 2 * j;
            float v0 = xb[(size_t)c0 * T_];
            float v1 = xb[(size_t)(c0 + 1) * T_];
            float l0 = v0 - (float)(_Float16)v0;
            float l1 = v1 - (float)(_Float16)v1;
            int ks = c0 >> 6, kk = c0 & 63;
            int off = tok * 128 + ((kk * 2) ^ swz_w);
            *(unsigned int*)(smem + (0 + ks) * 8192 + off) = pack2h(v0, v1);
            *(unsigned int*)(smem + (2 + ks) * 8192 + off) = pack2h(l0, l1);
        }
    }
    __syncthreads();

    f32x4 acc[4][2];
#pragma unroll
    for (int mt = 0; mt < 4; ++mt) { acc[mt][0] = (f32x4){0,0,0,0}; acc[mt][1] = (f32x4){0,0,0,0}; }

    float b1v[4][4], b2v[4][4];
    int   k1v[4][4];
#pragma unroll
    for (int mt = 0; mt < 4; ++mt)
#pragma unroll
        for (int r = 0; r < 4; ++r) { b1v[mt][r] = 3.4e38f; b2v[mt][r] = 3.4e38f; k1v[mt][r] = 0; }

    const int swz = (r15 & 7) << 4;

    // prologue: stage slab (ct=0, s=0) into buf0
    uint4 pf[4];
    {
        const unsigned short* srcp = cbh + ((size_t)((g * 2 + 0) * 8 + 0) << 13);
#pragma unroll
        for (int c = 0; c < 4; ++c)
            pf[c] = *(const uint4*)((const char*)srcp + wn * 4096 + c * 1024 + lane * 16);
#pragma unroll
        for (int c = 0; c < 4; ++c) {
            int off_s = wn * 4096 + c * 1024 + lane * 16;
            int row = off_s >> 7, col = off_s & 127;
            *(uint4*)(smem + 32768 + row * 128 + (col ^ ((row & 7) << 4))) = pf[c];
        }
    }
    __syncthreads();

    int cur = 0;
#pragma unroll 1
    for (int sg = 0; sg < 32; ++sg) {
        const int ct = sg >> 2, s = sg & 3;
        const int is_cbh = ((s & 1) == 0);
        // issue prefetch of next slab (global -> regs)
        if (sg < 31) {
            int sg1 = sg + 1, ct1 = sg1 >> 2, s1 = sg1 & 3;
            const unsigned short* srcp = ((s1 & 1) ? cbl : cbh)
                + ((size_t)((g * 2 + (s1 >> 1)) * 8 + ct1) << 13);
#pragma unroll
            for (int c = 0; c < 4; ++c)
                pf[c] = *(const uint4*)((const char*)srcp + wn * 4096 + c * 1024 + lane * 16);
        }

        // compute current buffer
        {
            const int abase_hi = (0 + (s >> 1)) * 8192;
            const int abase_lo = (2 + (s >> 1)) * 8192;
            const int bb = 32768 + cur * 16384;
#pragma unroll
            for (int sl = 0; sl < 2; ++sl) {
                const int colx = ((sl * 64) + q * 16) ^ swz;
                f16x8 bf0 = *(const f16x8*)(smem + bb + (wn * 32 + r15) * 128 + colx);
                f16x8 bf1 = *(const f16x8*)(smem + bb + (wn * 32 + 16 + r15) * 128 + colx);
#pragma unroll
                for (int mt = 0; mt < 4; ++mt) {
                    f16x8 ah = *(const f16x8*)(smem + abase_hi + (mt * 16 + r15) * 128 + colx);
                    acc[mt][0] = __builtin_amdgcn_mfma_f32_16x16x32_f16(ah, bf0, acc[mt][0], 0, 0, 0);
                    acc[mt][1] = __builtin_amdgcn_mfma_f32_16x16x32_f16(ah, bf1, acc[mt][1], 0, 0, 0);
                }
                if (is_cbh) {
#pragma unroll
                    for (int mt = 0; mt < 4; ++mt) {
                        f16x8 al = *(const f16x8*)(smem + abase_lo + (mt * 16 + r15) * 128 + colx);
                        acc[mt][0] = __builtin_amdgcn_mfma_f32_16x16x32_f16(al, bf0, acc[mt][0], 0, 0, 0);
                        acc[mt][1] = __builtin_amdgcn_mfma_f32_16x16x32_f16(al, bf1, acc[mt][1], 0, 0, 0);
                    }
                }
            }
        }

        // end of ct (s==3): fold accumulators into running top-2, reset acc
        if (s == 3) {
            float cn0 = cnorm[g * K_ + ct * 128 + wn * 32 + r15];
            float cn1 = cnorm[g * K_ + ct * 128 + wn * 32 + 16 + r15];
            int code0 = ct * 128 + wn * 32 + r15;
            int code1 = code0 + 16;
#pragma unroll
            for (int mt = 0; mt < 4; ++mt) {
#pragma unroll
                for (int r = 0; r < 4; ++r) {
                    float d0 = fmaf(-2.f, acc[mt][0][r], cn0);
                    b2v[mt][r] = fminf(b2v[mt][r], fmaxf(d0, b1v[mt][r]));
                    if (d0 < b1v[mt][r]) { k1v[mt][r] = code0; }
                    b1v[mt][r] = fminf(b1v[mt][r], d0);
                    float d1 = fmaf(-2.f, acc[mt][1][r], cn1);
                    b2v[mt][r] = fminf(b2v[mt][r], fmaxf(d1, b1v[mt][r]));
                    if (d1 < b1v[mt][r]) { k1v[mt][r] = code1; }
                    b1v[mt][r] = fminf(b1v[mt][r], d1);
                }
                acc[mt][0] = (f32x4){0,0,0,0};
                acc[mt][1] = (f32x4){0,0,0,0};
            }
        }

        // write prefetched slab into other buffer
        if (sg < 31) {
#pragma unroll
            for (int c = 0; c < 4; ++c) {
                int off_s = wn * 4096 + c * 1024 + lane * 16;
                int row = off_s >> 7, col = off_s & 127;
                *(uint4*)(smem + 32768 + (cur ^ 1) * 16384 + row * 128 + (col ^ ((row & 7) << 4))) = pf[c];
            }
        }
        __syncthreads();
        cur ^= 1;
    }

    // ---- cross-lane (16-lane group) top-2 merge
#pragma unroll
    for (int mt = 0; mt < 4; ++mt)
#pragma unroll
        for (int r = 0; r < 4; ++r) {
            float b1 = b1v[mt][r], b2 = b2v[mt][r];
            int   k1 = k1v[mt][r];
#pragma unroll
            for (int m = 1; m <= 8; m <<= 1) {
                float ob1 = __shfl_xor(b1, m, 64);
                float ob2 = __shfl_xor(b2, m, 64);
                int   ok1 = __shfl_xor(k1, m, 64);
                b2 = fminf(fminf(b2, ob2), fmaxf(b1, ob1));
                if (ob1 < b1) { k1 = ok1; }
                b1 = fminf(b1, ob1);
            }
            b1v[mt][r] = b1; b2v[mt][r] = b2; k1v[mt][r] = k1;
        }

    // ---- cross-wave merge via LDS scratch (reuse buf0 region)
    if (r15 == 0) {
#pragma unroll
        for (int mt = 0; mt < 4; ++mt)
#pragma unroll
            for (int r = 0; r < 4; ++r) {
                int tl = mt * 16 + q * 4 + r;
                float4 e = make_float4(b1v[mt][r], __int_as_float(k1v[mt][r]), b2v[mt][r], 0.f);
                *(float4*)(smem + 32768 + (wn * 64 + tl) * 16) = e;
            }
    }
    __syncthreads();
    if (tid < 64) {
        float4 e0 = *(float4*)(smem + 32768 + (0 * 64 + tid) * 16);
        float b1 = e0.x, b2 = e0.z;
        int   k1 = __float_as_int(e0.y);
#pragma unroll
        for (int wv = 1; wv < 4; ++wv) {
            float4 e = *(float4*)(smem + 32768 + (wv * 64 + tid) * 16);
            float eb1 = e.x, eb2 = e.z;
            int   ek1 = __float_as_int(e.y);
            b2 = fminf(fminf(b2, eb2), fmaxf(b1, eb1));
            if (eb1 < b1) { k1 = ek1; }
            b1 = fminf(b1, eb1);
        }
        int token = tt * 64 + tid;
        if (b2 - b1 <= DELTA) {
            unsigned int slot = atomicAdd(flag_count, 1u);
            flag_list[slot] = ((unsigned int)g << 16) | (unsigned int)token;
        } else {
            code_idx[(size_t)g * NTOK + token] = k1;
            atomicAdd(&counts[g * K_ + k1], 1.0f);
        }
    }
}

// ---------------------------------------------------------------------------
// K2: exact fp32 rescore of flagged (token, group) pairs. One wave per entry.
// ---------------------------------------------------------------------------
__global__ void __launch_bounds__(256) k_fallback(
        const float* __restrict__ x, const float* __restrict__ cb,
        const float* __restrict__ cnorm,
        const unsigned int* __restrict__ flag_count,
        const unsigned int* __restrict__ flag_list,
        int* __restrict__ code_idx, float* __restrict__ counts) {
    __shared__ float xrow[4][128];
    const int w = threadIdx.x >> 6, lane = threadIdx.x & 63;
    const unsigned int cnt = flag_count[0];
    const unsigned int wslot = blockIdx.x * 4 + w;

    for (unsigned int i = wslot; i < cnt; i += 512) {
        unsigned int e = flag_list[i];
        int g = e >> 16, token = e & 0xFFFF;
        int b = token >> 11, t = token & (T_ - 1);
        const float* xb = x + ((size_t)b * C_ + g * DG) * T_ + t;
        xrow[w][lane]      = xb[(size_t)lane * T_];
        xrow[w][lane + 64] = xb[(size_t)(lane + 64) * T_];
        asm volatile("s_waitcnt lgkmcnt(0)" ::: "memory");

        float best = 3.4e38f; int bestk = 0;
        for (int j = 0; j < 16; ++j) {
            int k = j * 64 + lane;
            const float4* crow = (const float4*)(cb + ((size_t)(g * K_ + k)) * DG);
            float a0 = 0.f, a1 = 0.f, a2 = 0.f, a3 = 0.f;
#pragma unroll
            for (int d4 = 0; d4 < DG / 4; ++d4) {
                float4 c4 = crow[d4];
                float4 xv = *(const float4*)&xrow[w][d4 * 4];
                a0 = fmaf(xv.x, c4.x, a0);
                a1 = fmaf(xv.y, c4.y, a1);
                a2 = fmaf(xv.z, c4.z, a2);
                a3 = fmaf(xv.w, c4.w, a3);
            }
            float dot = (a0 + a1) + (a2 + a3);
            float dist = fmaf(-2.f, dot, cnorm[g * K_ + k]);
            if (dist < best) { best = dist; bestk = k; }   // lane-local k ascending
        }
#pragma unroll
        for (int m = 32; m >= 1; m >>= 1) {
            float ob = __shfl_xor(best, m, 64);
            int   ok = __shfl_xor(bestk, m, 64);
            if (ob < best || (ob == best && ok < bestk)) { best = ob; bestk = ok; }
        }
        if (lane == 0) {
            code_idx[(size_t)g * NTOK + token] = bestk;
            atomicAdd(&counts[g * K_ + bestk], 1.0f);
        }
    }
}

// ---------------------------------------------------------------------------
// K3: dequantize + write out (N,C,T) + loss partial sums.
// ---------------------------------------------------------------------------
__global__ void __launch_bounds__(256) k_dequant(const float* __restrict__ x,
                                                 const float* __restrict__ cb,
                                                 const int* __restrict__ code_idx,
                                                 float* __restrict__ out,
                                                 float* __restrict__ loss_acc) {
    const int token = blockIdx.x * 256 + threadIdx.x;
    const int b     = token >> 11;
    const int t     = token & (T_ - 1);
    const size_t base = (size_t)b * C_ * T_ + t;

    float lsum = 0.f;
#pragma unroll
    for (int g = 0; g < G_; ++g) {
        const int idx = code_idx[(size_t)g * NTOK + token];
        const float4* row = (const float4*)(cb + ((size_t)g * K_ + idx) * DG);
        for (int d4 = 0; d4 < DG / 4; ++d4) {
            float4 v = row[d4];
            const int c = g * DG + d4 * 4;
            float x0 = x[base + (size_t)(c + 0) * T_];
            float x1 = x[base + (size_t)(c + 1) * T_];
            float x2 = x[base + (size_t)(c + 2) * T_];
            float x3 = x[base + (size_t)(c + 3) * T_];
            out[base + (size_t)(c + 0) * T_] = v.x;
            out[base + (size_t)(c + 1) * T_] = v.y;
            out[base + (size_t)(c + 2) * T_] = v.z;
            out[base + (size_t)(c + 3) * T_] = v.w;
            float d0 = v.x - x0, d1 = v.y - x1, d2 = v.z - x2, d3 = v.w - x3;
            lsum += d0 * d0 + d1 * d1 + d2 * d2 + d3 * d3;
        }
    }
#pragma unroll
    for (int off = 32; off >= 1; off >>= 1)
        lsum += __shfl_down(lsum, off, 64);
    if ((threadIdx.x & 63) == 0) atomicAdd(loss_acc, lsum);
}

// ---------------------------------------------------------------------------
// K4: finalize loss & perplexity scalars.
// ---------------------------------------------------------------------------
__global__ void k_final(const float* __restrict__ counts,
                        const float* __restrict__ loss_acc,
                        float* __restrict__ out_scalars) {
    const int w    = threadIdx.x >> 6;
    const int lane = threadIdx.x & 63;
    float s = 0.f;
    for (int j = lane; j < K_; j += 64) {
        float p = counts[w * K_ + j] * (1.0f / NTOK);
        s += p * logf(p + 1e-10f);
    }
#pragma unroll
    for (int off = 32; off >= 1; off >>= 1)
        s += __shfl_down(s, off, 64);
    __shared__ float sg[4];
    if (lane == 0) sg[w] = s;
    __syncthreads();
    if (threadIdx.x == 0) {
        float perp = 0.f;
#pragma unroll
        for (int g = 0; g < G_; ++g) perp += expf(-sg[g]);
        perp *= 0.25f;
        float loss = 1.25f * loss_acc[0] / (float)((size_t)NTOK * C_);
        out_scalars[0] = loss;
        out_scalars[1] = perp;
    }
}

// ---------------------------------------------------------------------------
extern "C" void kernel_launch(void* const* d_in, const int* in_sizes, int n_in,
                              void* d_out, int out_size, void* d_ws, size_t ws_size,
                              hipStream_t stream) {
    const float* x  = (const float*)d_in[0];
    const float* cb = (const float*)d_in[1];
    float* out = (float*)d_out;

    char* ws = (char*)d_ws;
    int*            code_idx   = (int*)(ws + OFF_CODEIDX);
    float*          cnorm      = (float*)(ws + OFF_CNORM);
    float*          counts     = (float*)(ws + OFF_COUNTS);
    float*          loss_acc   = (float*)(ws + OFF_LOSS);
    unsigned int*   flag_count = (unsigned int*)(ws + OFF_FLAGCNT);
    unsigned int*   flag_list  = (unsigned int*)(ws + OFF_FLAGS);
    unsigned short* cbh        = (unsigned short*)(ws + OFF_CBH);
    unsigned short* cbl        = (unsigned short*)(ws + OFF_CBL);

    // zero counts + loss_acc + flag_count (ws is re-poisoned before each launch)
    hipMemsetAsync(ws + OFF_COUNTS, 0, (OFF_FLAGCNT + 4) - OFF_COUNTS, stream);

    k_cnorm<<<G_ * K_ / 256, 256, 0, stream>>>(cb, cnorm);
    k_prep_cb<<<dim3(8, G_), 256, 0, stream>>>(cb, cbh, cbl);
    k_screen<<<dim3(NTOK / 64, G_), 256, 0, stream>>>(x, cbh, cbl, cnorm,
                                                      code_idx, counts, flag_count, flag_list);
    k_fallback<<<128, 256, 0, stream>>>(x, cb, cnorm, flag_count, flag_list, code_idx, counts);
    k_dequant<<<NTOK / 256, 256, 0, stream>>>(x, cb, code_idx, out, loss_acc);
    k_final<<<1, 256, 0, stream>>>(counts, loss_acc, out + NCT);
}